// Round 7
// baseline (1021.028 us; speedup 1.0000x reference)
//
#include <hip/hip_runtime.h>
#include <cstddef>

#define NGRAPH  4
#define NPG     50000        // nodes per graph
#define NNODES  200000
#define BNECK   64
#define FFN     128
#define COLS    800000       // INPUT_SIZE * HIDDEN[2]
#define NEDGE   3200000
#define H2      16
#define H1      8

// ---- ELL path params ----
#define MAXDEG  32           // Poisson(16): P(deg>32) ~ 1e-4/node -> ~20 overflow nodes
#define OVCAP   8192
#define RANGES  16           // 2 phases x 8 XCDs; 3.2MB ELL window per XCD < 4MB L2
#define RW      (NNODES / RANGES)           // 12500 nodes per range
#define EPB     8192                        // edges per place block
#define CH      ((NEDGE + EPB - 1) / EPB)   // 391 chunks

// ---- CSR fallback params ----
#define SCAN_B  512
#define NB      ((NNODES + SCAN_B - 1) / SCAN_B)

__device__ __forceinline__ float elu(float x) {
    return x > 0.f ? x : expm1f(x);
}

// Merged: block 0 = fc1 (z1 = elu(x@fc1_w+b)); other blocks zero cnt, set degf=1, ovc=0.
__global__ void k_init(const float* __restrict__ x, const float* __restrict__ w,
                       const float* __restrict__ b, float* __restrict__ z1,
                       int* __restrict__ cnt, float* __restrict__ degf,
                       int* __restrict__ ovc) {
    if (blockIdx.x == 0) {
        int t = threadIdx.x;                 // 512 threads
        int g = t >> 7, j = t & 127;
        float acc = b[j];
        #pragma unroll 8
        for (int i = 0; i < BNECK; ++i)
            acc = fmaf(x[g * BNECK + i], w[i * FFN + j], acc);
        z1[t] = elu(acc);
        if (t == 0) *ovc = 0;
    } else {
        int i = (blockIdx.x - 1) * 512 + threadIdx.x;
        if (i < NNODES) { cnt[i] = 0; degf[i] = 1.0f; }   // 1.0 = self-loop weight
    }
}

// ======================= ELL build (XCD-windowed) =======================
// b = ((p*CH + chunk)*8 + x): consecutive b -> different XCDs (bid&7 heuristic);
// XCD x in phase p owns col range (p*8+x)*RW .. +RW. Also accumulates degf (L2-local).
__global__ void k_place_ell(const int* __restrict__ row, const int* __restrict__ col,
                            const float* __restrict__ ew,
                            int* __restrict__ cnt, float* __restrict__ degf,
                            int2* __restrict__ ell,
                            int* __restrict__ ovc, int3* __restrict__ ovf) {
    int b = blockIdx.x;
    int x = b & 7;
    int q = b >> 3;
    int p = q / CH;
    int chunk = q - p * CH;
    int c0 = (p * 8 + x) * RW;
    int c1 = c0 + RW;
    int base = chunk * EPB;
    const int4* col4 = reinterpret_cast<const int4*>(col);
    #pragma unroll
    for (int i = 0; i < EPB / 1024; ++i) {       // 8 iters, 4 edges/thread each
        int e = base + i * 1024 + threadIdx.x * 4;
        if (e < NEDGE) {                         // NEDGE % 4 == 0 -> whole int4 valid
            int4 c4 = col4[e >> 2];
            #pragma unroll
            for (int k = 0; k < 4; ++k) {
                int c = (k == 0) ? c4.x : (k == 1) ? c4.y : (k == 2) ? c4.z : c4.w;
                if (c >= c0 && c < c1) {
                    int ee = e + k;
                    float w = ew[ee];
                    atomicAdd(&degf[c], w);
                    int pos = atomicAdd(&cnt[c], 1);
                    if (pos < MAXDEG) {
                        int2 ent; ent.x = row[ee]; ent.y = __float_as_int(w);
                        ell[(size_t)c * MAXDEG + pos] = ent;
                    } else {
                        int o = atomicAdd(ovc, 1);
                        if (o < OVCAP) {
                            int3 ent3; ent3.x = c; ent3.y = row[ee]; ent3.z = __float_as_int(w);
                            ovf[o] = ent3;
                        }
                    }
                }
            }
        }
    }
}

__global__ void k_dinv(const float* __restrict__ degf, float* __restrict__ dinv) {
    int n = blockIdx.x * blockDim.x + threadIdx.x;
    if (n < NNODES) dinv[n] = rsqrtf(degf[n]);   // degf >= 1 always
}

// ======================= big GEMM + conv0 linear (shared by both paths) =======================
__global__ __launch_bounds__(256) void k_fc2(
    const float* __restrict__ z1, const float* __restrict__ w2,
    const float* __restrict__ b2, const float* __restrict__ cw0,
    const float* __restrict__ dinv,
    float* __restrict__ hws, float* __restrict__ acc0)
{
    __shared__ float s_z1[NGRAPH * FFN];   // 512
    __shared__ float s_cw[H2 * H1];        // 128
    __shared__ float s_h[NGRAPH][1024];    // 16 KB

    int t = threadIdx.x;
    for (int i = t; i < NGRAPH * FFN; i += 256) s_z1[i] = z1[i];
    if (t < H2 * H1) s_cw[t] = cw0[t];
    __syncthreads();

    int j0 = blockIdx.x * 1024;
    int jj = j0 + t * 4;
    if (jj < COLS) {
        float4 a0 = {0,0,0,0}, a1 = {0,0,0,0}, a2 = {0,0,0,0}, a3 = {0,0,0,0};
        #pragma unroll 4
        for (int i = 0; i < FFN; ++i) {
            const float4 wv = *reinterpret_cast<const float4*>(&w2[(size_t)i * COLS + jj]);
            float zg0 = s_z1[0 * FFN + i];
            float zg1 = s_z1[1 * FFN + i];
            float zg2 = s_z1[2 * FFN + i];
            float zg3 = s_z1[3 * FFN + i];
            a0.x = fmaf(zg0, wv.x, a0.x); a0.y = fmaf(zg0, wv.y, a0.y);
            a0.z = fmaf(zg0, wv.z, a0.z); a0.w = fmaf(zg0, wv.w, a0.w);
            a1.x = fmaf(zg1, wv.x, a1.x); a1.y = fmaf(zg1, wv.y, a1.y);
            a1.z = fmaf(zg1, wv.z, a1.z); a1.w = fmaf(zg1, wv.w, a1.w);
            a2.x = fmaf(zg2, wv.x, a2.x); a2.y = fmaf(zg2, wv.y, a2.y);
            a2.z = fmaf(zg2, wv.z, a2.z); a2.w = fmaf(zg2, wv.w, a2.w);
            a3.x = fmaf(zg3, wv.x, a3.x); a3.y = fmaf(zg3, wv.y, a3.y);
            a3.z = fmaf(zg3, wv.z, a3.z); a3.w = fmaf(zg3, wv.w, a3.w);
        }
        const float4 bv = *reinterpret_cast<const float4*>(&b2[jj]);
        s_h[0][t*4+0] = elu(a0.x + bv.x); s_h[0][t*4+1] = elu(a0.y + bv.y);
        s_h[0][t*4+2] = elu(a0.z + bv.z); s_h[0][t*4+3] = elu(a0.w + bv.w);
        s_h[1][t*4+0] = elu(a1.x + bv.x); s_h[1][t*4+1] = elu(a1.y + bv.y);
        s_h[1][t*4+2] = elu(a1.z + bv.z); s_h[1][t*4+3] = elu(a1.w + bv.w);
        s_h[2][t*4+0] = elu(a2.x + bv.x); s_h[2][t*4+1] = elu(a2.y + bv.y);
        s_h[2][t*4+2] = elu(a2.z + bv.z); s_h[2][t*4+3] = elu(a2.w + bv.w);
        s_h[3][t*4+0] = elu(a3.x + bv.x); s_h[3][t*4+1] = elu(a3.y + bv.y);
        s_h[3][t*4+2] = elu(a3.z + bv.z); s_h[3][t*4+3] = elu(a3.w + bv.w);
    }
    __syncthreads();

    int nbase = j0 >> 4;
    for (int o = t; o < NGRAPH * 64 * H1; o += 256) {
        int g  = o >> 9;
        int lo = o & 511;
        int nl = lo >> 3;
        int m  = lo & 7;
        int nloc = nbase + nl;
        if (nloc < NPG) {
            const float* hr = &s_h[g][nl * 16];
            float s = 0.f;
            #pragma unroll
            for (int k = 0; k < H2; ++k) s = fmaf(hr[k], s_cw[k * H1 + m], s);
            int node = g * NPG + nloc;
            float di = dinv[node];
            hws[node * H1 + m]  = s * di;        // pre-scaled by dinv[src]
            acc0[node * H1 + m] = s * (di * di); // self-loop term
        }
    }
}

// ======================= ELL gathers (int4 paired-entry reads) =======================
__device__ __forceinline__ void acc_msg(int r, float w, const float* __restrict__ hws,
                                        float4& mA, float4& mB) {
    const float4 ha = *reinterpret_cast<const float4*>(&hws[r * H1]);
    const float4 hb = *reinterpret_cast<const float4*>(&hws[r * H1 + 4]);
    mA.x = fmaf(ha.x, w, mA.x); mA.y = fmaf(ha.y, w, mA.y);
    mA.z = fmaf(ha.z, w, mA.z); mA.w = fmaf(ha.w, w, mA.w);
    mB.x = fmaf(hb.x, w, mB.x); mB.y = fmaf(hb.y, w, mB.y);
    mB.z = fmaf(hb.z, w, mB.z); mB.w = fmaf(hb.w, w, mB.w);
}

__global__ void k_gather0_ell(const int* __restrict__ cnt, const int2* __restrict__ ell,
                              const int* __restrict__ ovc, const int3* __restrict__ ovf,
                              const float* __restrict__ hws, const float* __restrict__ acc0,
                              const float* __restrict__ b0, const float* __restrict__ cw1,
                              const float* __restrict__ dinv, float* __restrict__ h1s) {
    int n = blockIdx.x * blockDim.x + threadIdx.x;
    if (n >= NNODES) return;
    int d = cnt[n];
    int m = d < MAXDEG ? d : MAXDEG;
    const int4* en4 = reinterpret_cast<const int4*>(&ell[(size_t)n * MAXDEG]);
    float4 mA = {0,0,0,0}, mB = {0,0,0,0};
    int h = m >> 1;
    for (int j = 0; j < h; ++j) {
        int4 pr = en4[j];
        acc_msg(pr.x, __int_as_float(pr.y), hws, mA, mB);
        acc_msg(pr.z, __int_as_float(pr.w), hws, mA, mB);
    }
    if (m & 1) {
        int2 ent = ell[(size_t)n * MAXDEG + m - 1];
        acc_msg(ent.x, __int_as_float(ent.y), hws, mA, mB);
    }
    if (d > MAXDEG) {
        int oc = *ovc; if (oc > OVCAP) oc = OVCAP;
        for (int j = 0; j < oc; ++j)
            if (ovf[j].x == n) acc_msg(ovf[j].y, __int_as_float(ovf[j].z), hws, mA, mB);
    }
    float dc = dinv[n];
    const float4 sA = *reinterpret_cast<const float4*>(&acc0[n * H1]);
    const float4 sB = *reinterpret_cast<const float4*>(&acc0[n * H1 + 4]);
    float s = 0.f;
    s = fmaf(elu(sA.x + dc * mA.x + b0[0]), cw1[0], s);
    s = fmaf(elu(sA.y + dc * mA.y + b0[1]), cw1[1], s);
    s = fmaf(elu(sA.z + dc * mA.z + b0[2]), cw1[2], s);
    s = fmaf(elu(sA.w + dc * mA.w + b0[3]), cw1[3], s);
    s = fmaf(elu(sB.x + dc * mB.x + b0[4]), cw1[4], s);
    s = fmaf(elu(sB.y + dc * mB.y + b0[5]), cw1[5], s);
    s = fmaf(elu(sB.z + dc * mB.z + b0[6]), cw1[6], s);
    s = fmaf(elu(sB.w + dc * mB.w + b0[7]), cw1[7], s);
    h1s[n] = s * dc;     // pre-scaled by dinv[src] for conv1
}

__global__ void k_gather1_ell(const int* __restrict__ cnt, const int2* __restrict__ ell,
                              const int* __restrict__ ovc, const int3* __restrict__ ovf,
                              const float* __restrict__ h1s, const float* __restrict__ dinv,
                              const float* __restrict__ cb1, float* __restrict__ out) {
    int n = blockIdx.x * blockDim.x + threadIdx.x;
    if (n >= NNODES) return;
    int d = cnt[n];
    int m = d < MAXDEG ? d : MAXDEG;
    const int4* en4 = reinterpret_cast<const int4*>(&ell[(size_t)n * MAXDEG]);
    float a = h1s[n];                    // self-loop term
    int h = m >> 1;
    for (int j = 0; j < h; ++j) {
        int4 pr = en4[j];
        a = fmaf(h1s[pr.x], __int_as_float(pr.y), a);
        a = fmaf(h1s[pr.z], __int_as_float(pr.w), a);
    }
    if (m & 1) {
        int2 ent = ell[(size_t)n * MAXDEG + m - 1];
        a = fmaf(h1s[ent.x], __int_as_float(ent.y), a);
    }
    if (d > MAXDEG) {
        int oc = *ovc; if (oc > OVCAP) oc = OVCAP;
        for (int j = 0; j < oc; ++j)
            if (ovf[j].x == n) a = fmaf(h1s[ovf[j].y], __int_as_float(ovf[j].z), a);
    }
    out[n] = cb1[0] + a * dinv[n];
}

// ======================= CSR fallback (round-4 pipeline, proven) =======================
__global__ void k_fc1(const float* __restrict__ x, const float* __restrict__ w,
                      const float* __restrict__ b, float* __restrict__ z1) {
    int t = threadIdx.x;
    int g = t >> 7, j = t & 127;
    float acc = b[j];
    #pragma unroll 8
    for (int i = 0; i < BNECK; ++i)
        acc = fmaf(x[g * BNECK + i], w[i * FFN + j], acc);
    z1[t] = elu(acc);
}

__global__ void k_zero(int* __restrict__ p, int n) {
    int i = blockIdx.x * blockDim.x + threadIdx.x;
    if (i < n) p[i] = 0;
}

__global__ void k_hist(const int* __restrict__ col, int* __restrict__ cnt) {
    int e = blockIdx.x * blockDim.x + threadIdx.x;
    if (e < NEDGE) atomicAdd(&cnt[col[e]], 1);
}

__global__ void k_bsum(const int* __restrict__ cnt, int* __restrict__ bsum) {
    __shared__ int s[SCAN_B];
    int t = threadIdx.x;
    int i = blockIdx.x * SCAN_B + t;
    s[t] = (i < NNODES) ? cnt[i] : 0;
    __syncthreads();
    for (int st = SCAN_B / 2; st > 0; st >>= 1) {
        if (t < st) s[t] += s[t + st];
        __syncthreads();
    }
    if (t == 0) bsum[blockIdx.x] = s[0];
}

__global__ void k_btop(const int* __restrict__ bsum, int* __restrict__ bstart) {
    __shared__ int s[SCAN_B];
    int t = threadIdx.x;
    int v = (t < NB) ? bsum[t] : 0;
    s[t] = v;
    __syncthreads();
    for (int st = 1; st < SCAN_B; st <<= 1) {
        int x = (t >= st) ? s[t - st] : 0;
        __syncthreads();
        s[t] += x;
        __syncthreads();
    }
    if (t < NB) bstart[t] = s[t] - v;
}

__global__ void k_bscan(int* __restrict__ cnt, const int* __restrict__ bstart) {
    __shared__ int s[SCAN_B];
    int t = threadIdx.x;
    int i = blockIdx.x * SCAN_B + t;
    int v = (i < NNODES) ? cnt[i] : 0;
    s[t] = v;
    __syncthreads();
    for (int st = 1; st < SCAN_B; st <<= 1) {
        int x = (t >= st) ? s[t - st] : 0;
        __syncthreads();
        s[t] += x;
        __syncthreads();
    }
    if (i < NNODES) cnt[i] = bstart[blockIdx.x] + s[t] - v;
}

__global__ void k_place(const int* __restrict__ row, const int* __restrict__ col,
                        const float* __restrict__ ew,
                        int* __restrict__ offs, int2* __restrict__ csr) {
    int e = blockIdx.x * blockDim.x + threadIdx.x;
    if (e >= NEDGE) return;
    int c = col[e];
    int pos = atomicAdd(&offs[c], 1);
    int2 ent;
    ent.x = row[e];
    ent.y = __float_as_int(ew[e]);
    csr[pos] = ent;
}

__global__ void k_deg(const int* __restrict__ offs, const int2* __restrict__ csr,
                      float* __restrict__ dinv) {
    int n = blockIdx.x * blockDim.x + threadIdx.x;
    if (n >= NNODES) return;
    int s0 = n ? offs[n - 1] : 0;
    int e0 = offs[n];
    float d = 1.0f;
    for (int j = s0; j < e0; ++j) d += __int_as_float(csr[j].y);
    dinv[n] = rsqrtf(d);
}

__global__ void k_gather0(const int* __restrict__ offs, const int2* __restrict__ csr,
                          const float* __restrict__ hws, const float* __restrict__ acc0,
                          const float* __restrict__ b0, const float* __restrict__ cw1,
                          const float* __restrict__ dinv, float* __restrict__ h1s) {
    int n = blockIdx.x * blockDim.x + threadIdx.x;
    if (n >= NNODES) return;
    int s0 = n ? offs[n - 1] : 0;
    int e0 = offs[n];
    float4 mA = {0,0,0,0}, mB = {0,0,0,0};
    for (int j = s0; j < e0; ++j) {
        int2 ent = csr[j];
        acc_msg(ent.x, __int_as_float(ent.y), hws, mA, mB);
    }
    float dc = dinv[n];
    const float4 sA = *reinterpret_cast<const float4*>(&acc0[n * H1]);
    const float4 sB = *reinterpret_cast<const float4*>(&acc0[n * H1 + 4]);
    float s = 0.f;
    s = fmaf(elu(sA.x + dc * mA.x + b0[0]), cw1[0], s);
    s = fmaf(elu(sA.y + dc * mA.y + b0[1]), cw1[1], s);
    s = fmaf(elu(sA.z + dc * mA.z + b0[2]), cw1[2], s);
    s = fmaf(elu(sA.w + dc * mA.w + b0[3]), cw1[3], s);
    s = fmaf(elu(sB.x + dc * mB.x + b0[4]), cw1[4], s);
    s = fmaf(elu(sB.y + dc * mB.y + b0[5]), cw1[5], s);
    s = fmaf(elu(sB.z + dc * mB.z + b0[6]), cw1[6], s);
    s = fmaf(elu(sB.w + dc * mB.w + b0[7]), cw1[7], s);
    h1s[n] = s * dc;
}

__global__ void k_gather1(const int* __restrict__ offs, const int2* __restrict__ csr,
                          const float* __restrict__ h1s, const float* __restrict__ dinv,
                          const float* __restrict__ cb1, float* __restrict__ out) {
    int n = blockIdx.x * blockDim.x + threadIdx.x;
    if (n >= NNODES) return;
    int s0 = n ? offs[n - 1] : 0;
    int e0 = offs[n];
    float a = h1s[n];
    for (int j = s0; j < e0; ++j) {
        int2 ent = csr[j];
        a = fmaf(h1s[ent.x], __int_as_float(ent.y), a);
    }
    out[n] = cb1[0] + a * dinv[n];
}

extern "C" void kernel_launch(void* const* d_in, const int* in_sizes, int n_in,
                              void* d_out, int out_size, void* d_ws, size_t ws_size,
                              hipStream_t stream) {
    const float* x    = (const float*)d_in[0];
    const int*   ei   = (const int*)d_in[1];
    const float* ew   = (const float*)d_in[2];
    const float* fc1w = (const float*)d_in[3];
    const float* fc1b = (const float*)d_in[4];
    const float* fc2w = (const float*)d_in[5];
    const float* fc2b = (const float*)d_in[6];
    const float* cw0  = (const float*)d_in[7];
    const float* cb0  = (const float*)d_in[8];
    const float* cw1  = (const float*)d_in[9];
    const float* cb1  = (const float*)d_in[10];
    float* out = (float*)d_out;

    const int* row = ei;
    const int* col = ei + NEDGE;

    // common workspace prefix (4B units)
    float* ws    = (float*)d_ws;
    float* z1    = ws;                          // 512
    float* dinv  = ws + 512;                    // 200000
    float* hws   = dinv + NNODES;               // 1.6M
    float* acc0  = hws + (size_t)NNODES * H1;   // 1.6M
    float* h1s   = acc0 + (size_t)NNODES * H1;  // 200000

    // ELL layout: prefix + cnt + degf + ovc + ovf + ell
    size_t ell_units = 512 + NNODES + 2u * (size_t)NNODES * H1 + NNODES
                     + NNODES + NNODES + 8 + (3u * OVCAP)
                     + 2u * (size_t)NNODES * MAXDEG;
    bool use_ell = ws_size >= ell_units * 4u + 256u;

    if (use_ell) {
        int*   cnt  = (int*)(h1s + NNODES);        // 200000
        float* degf = (float*)(cnt + NNODES);      // 200000
        int*   ovc  = (int*)(degf + NNODES);       // 1 (+7 pad)
        int3*  ovf  = (int3*)(ovc + 8);            // 8192 x 12B
        int2*  ell  = (int2*)((int*)ovf + 3 * OVCAP); // 200000*32 x 8B

        k_init<<<1 + (NNODES + 511) / 512, 512, 0, stream>>>(x, fc1w, fc1b, z1, cnt, degf, ovc);
        k_place_ell<<<2 * CH * 8, 256, 0, stream>>>(row, col, ew, cnt, degf, ell, ovc, ovf);
        k_dinv<<<(NNODES + 255) / 256, 256, 0, stream>>>(degf, dinv);
        k_fc2<<<(COLS + 1023) / 1024, 256, 0, stream>>>(z1, fc2w, fc2b, cw0, dinv, hws, acc0);
        k_gather0_ell<<<(NNODES + 255) / 256, 256, 0, stream>>>(cnt, ell, ovc, ovf, hws, acc0,
                                                                cb0, cw1, dinv, h1s);
        k_gather1_ell<<<(NNODES + 255) / 256, 256, 0, stream>>>(cnt, ell, ovc, ovf, h1s, dinv,
                                                                cb1, out);
    } else {
        int*   offs  = (int*)(h1s + NNODES);        // 200000
        int*   bsum  = offs + NNODES;               // 512
        int*   bst   = bsum + SCAN_B;               // 512
        int2*  csr   = (int2*)(bst + SCAN_B);       // 3.2M x 8B

        k_fc1 <<<1, 512, 0, stream>>>(x, fc1w, fc1b, z1);
        k_zero<<<(NNODES + 255) / 256, 256, 0, stream>>>(offs, NNODES);
        k_hist<<<(NEDGE + 255) / 256, 256, 0, stream>>>(col, offs);
        k_bsum<<<NB, SCAN_B, 0, stream>>>(offs, bsum);
        k_btop<<<1, SCAN_B, 0, stream>>>(bsum, bst);
        k_bscan<<<NB, SCAN_B, 0, stream>>>(offs, bst);
        k_place<<<(NEDGE + 255) / 256, 256, 0, stream>>>(row, col, ew, offs, csr);
        k_deg<<<(NNODES + 255) / 256, 256, 0, stream>>>(offs, csr, dinv);
        k_fc2<<<(COLS + 1023) / 1024, 256, 0, stream>>>(z1, fc2w, fc2b, cw0, dinv, hws, acc0);
        k_gather0<<<(NNODES + 255) / 256, 256, 0, stream>>>(offs, csr, hws, acc0, cb0, cw1, dinv, h1s);
        k_gather1<<<(NNODES + 255) / 256, 256, 0, stream>>>(offs, csr, h1s, dinv, cb1, out);
    }
}

// Round 9
// 900.690 us; speedup vs baseline: 1.1336x; 1.1336x over previous
//
#include <hip/hip_runtime.h>
#include <cstddef>

#define NGRAPH  4
#define NPG     50000        // nodes per graph
#define NNODES  200000
#define BNECK   64
#define FFN     128
#define COLS    800000       // INPUT_SIZE * HIDDEN[2]
#define NEDGE   3200000
#define H2      16
#define H1      8

// ---- ELL path params ----
#define MAXDEG  32           // Poisson(16): P(deg>32) ~ 1e-4/node -> ~20 overflow nodes
#define OVCAP   8192
#define RANGES  16           // 2 phases x 8 XCDs; 3.2MB ELL window per XCD < 4MB L2
#define RW      (NNODES / RANGES)           // 12500 nodes per range
#define EPB     8192                        // edges per place block
#define CH      ((NEDGE + EPB - 1) / EPB)   // 391 chunks

// ---- CSR fallback params ----
#define SCAN_B  512
#define NB      ((NNODES + SCAN_B - 1) / SCAN_B)

__device__ __forceinline__ float elu(float x) {
    return x > 0.f ? x : expm1f(x);
}

// Merged: block 0 = fc1 (z1 = elu(x@fc1_w+b)); other blocks zero cnt, ovc=0.
// NOTE: no degf — degree is summed from ELL afterwards. Atomics are the
// expensive resource (~20 G/s flat): place must issue exactly ONE per edge.
__global__ void k_init(const float* __restrict__ x, const float* __restrict__ w,
                       const float* __restrict__ b, float* __restrict__ z1,
                       int* __restrict__ cnt, int* __restrict__ ovc) {
    if (blockIdx.x == 0) {
        int t = threadIdx.x;                 // 512 threads
        int g = t >> 7, j = t & 127;
        float acc = b[j];
        #pragma unroll 8
        for (int i = 0; i < BNECK; ++i)
            acc = fmaf(x[g * BNECK + i], w[i * FFN + j], acc);
        z1[t] = elu(acc);
        if (t == 0) *ovc = 0;
    } else {
        int i = (blockIdx.x - 1) * 512 + threadIdx.x;
        if (i < NNODES) cnt[i] = 0;
    }
}

// ======================= ELL build (XCD-windowed) =======================
// b = ((p*CH + chunk)*8 + x): consecutive b -> different XCDs (bid&7 heuristic);
// XCD x in phase p owns col range (p*8+x)*RW .. +RW.
__global__ void k_place_ell(const int* __restrict__ row, const int* __restrict__ col,
                            const float* __restrict__ ew,
                            int* __restrict__ cnt, int2* __restrict__ ell,
                            int* __restrict__ ovc, int3* __restrict__ ovf) {
    int b = blockIdx.x;
    int x = b & 7;
    int q = b >> 3;
    int p = q / CH;
    int chunk = q - p * CH;
    int c0 = (p * 8 + x) * RW;
    int c1 = c0 + RW;
    int base = chunk * EPB;
    const int4* col4 = reinterpret_cast<const int4*>(col);
    #pragma unroll
    for (int i = 0; i < EPB / 1024; ++i) {       // 8 iters, 4 edges/thread each
        int e = base + i * 1024 + threadIdx.x * 4;
        if (e < NEDGE) {                         // NEDGE % 4 == 0 -> whole int4 valid
            int4 c4 = col4[e >> 2];
            #pragma unroll
            for (int k = 0; k < 4; ++k) {
                int c = (k == 0) ? c4.x : (k == 1) ? c4.y : (k == 2) ? c4.z : c4.w;
                if (c >= c0 && c < c1) {
                    int ee = e + k;
                    int pos = atomicAdd(&cnt[c], 1);
                    if (pos < MAXDEG) {
                        int2 ent; ent.x = row[ee]; ent.y = __float_as_int(ew[ee]);
                        ell[(size_t)c * MAXDEG + pos] = ent;
                    } else {
                        int o = atomicAdd(ovc, 1);
                        if (o < OVCAP) {
                            int3 ent3; ent3.x = c; ent3.y = row[ee]; ent3.z = __float_as_int(ew[ee]);
                            ovf[o] = ent3;
                        }
                    }
                }
            }
        }
    }
}

// deg[n] = 1 + sum of in-edge weights (from ELL + overflow); dinv = rsqrt.
__global__ void k_deg_ell(const int* __restrict__ cnt, const int2* __restrict__ ell,
                          const int* __restrict__ ovc, const int3* __restrict__ ovf,
                          float* __restrict__ dinv) {
    int n = blockIdx.x * blockDim.x + threadIdx.x;
    if (n >= NNODES) return;
    int d = cnt[n];
    int m = d < MAXDEG ? d : MAXDEG;
    const int2* en = &ell[(size_t)n * MAXDEG];
    float s = 1.0f;                      // self loop
    for (int j = 0; j < m; ++j) s += __int_as_float(en[j].y);
    if (d > MAXDEG) {
        int oc = *ovc; if (oc > OVCAP) oc = OVCAP;
        for (int j = 0; j < oc; ++j)
            if (ovf[j].x == n) s += __int_as_float(ovf[j].z);
    }
    dinv[n] = rsqrtf(s);
}

// ======================= big GEMM + conv0 linear (shared by both paths) =======================
__global__ __launch_bounds__(256) void k_fc2(
    const float* __restrict__ z1, const float* __restrict__ w2,
    const float* __restrict__ b2, const float* __restrict__ cw0,
    const float* __restrict__ dinv,
    float* __restrict__ hws, float* __restrict__ acc0)
{
    __shared__ float s_z1[NGRAPH * FFN];   // 512
    __shared__ float s_cw[H2 * H1];        // 128
    __shared__ float s_h[NGRAPH][1024];    // 16 KB

    int t = threadIdx.x;
    for (int i = t; i < NGRAPH * FFN; i += 256) s_z1[i] = z1[i];
    if (t < H2 * H1) s_cw[t] = cw0[t];
    __syncthreads();

    int j0 = blockIdx.x * 1024;
    int jj = j0 + t * 4;
    if (jj < COLS) {
        float4 a0 = {0,0,0,0}, a1 = {0,0,0,0}, a2 = {0,0,0,0}, a3 = {0,0,0,0};
        #pragma unroll 4
        for (int i = 0; i < FFN; ++i) {
            const float4 wv = *reinterpret_cast<const float4*>(&w2[(size_t)i * COLS + jj]);
            float zg0 = s_z1[0 * FFN + i];
            float zg1 = s_z1[1 * FFN + i];
            float zg2 = s_z1[2 * FFN + i];
            float zg3 = s_z1[3 * FFN + i];
            a0.x = fmaf(zg0, wv.x, a0.x); a0.y = fmaf(zg0, wv.y, a0.y);
            a0.z = fmaf(zg0, wv.z, a0.z); a0.w = fmaf(zg0, wv.w, a0.w);
            a1.x = fmaf(zg1, wv.x, a1.x); a1.y = fmaf(zg1, wv.y, a1.y);
            a1.z = fmaf(zg1, wv.z, a1.z); a1.w = fmaf(zg1, wv.w, a1.w);
            a2.x = fmaf(zg2, wv.x, a2.x); a2.y = fmaf(zg2, wv.y, a2.y);
            a2.z = fmaf(zg2, wv.z, a2.z); a2.w = fmaf(zg2, wv.w, a2.w);
            a3.x = fmaf(zg3, wv.x, a3.x); a3.y = fmaf(zg3, wv.y, a3.y);
            a3.z = fmaf(zg3, wv.z, a3.z); a3.w = fmaf(zg3, wv.w, a3.w);
        }
        const float4 bv = *reinterpret_cast<const float4*>(&b2[jj]);
        s_h[0][t*4+0] = elu(a0.x + bv.x); s_h[0][t*4+1] = elu(a0.y + bv.y);
        s_h[0][t*4+2] = elu(a0.z + bv.z); s_h[0][t*4+3] = elu(a0.w + bv.w);
        s_h[1][t*4+0] = elu(a1.x + bv.x); s_h[1][t*4+1] = elu(a1.y + bv.y);
        s_h[1][t*4+2] = elu(a1.z + bv.z); s_h[1][t*4+3] = elu(a1.w + bv.w);
        s_h[2][t*4+0] = elu(a2.x + bv.x); s_h[2][t*4+1] = elu(a2.y + bv.y);
        s_h[2][t*4+2] = elu(a2.z + bv.z); s_h[2][t*4+3] = elu(a2.w + bv.w);
        s_h[3][t*4+0] = elu(a3.x + bv.x); s_h[3][t*4+1] = elu(a3.y + bv.y);
        s_h[3][t*4+2] = elu(a3.z + bv.z); s_h[3][t*4+3] = elu(a3.w + bv.w);
    }
    __syncthreads();

    int nbase = j0 >> 4;
    for (int o = t; o < NGRAPH * 64 * H1; o += 256) {
        int g  = o >> 9;
        int lo = o & 511;
        int nl = lo >> 3;
        int m  = lo & 7;
        int nloc = nbase + nl;
        if (nloc < NPG) {
            const float* hr = &s_h[g][nl * 16];
            float s = 0.f;
            #pragma unroll
            for (int k = 0; k < H2; ++k) s = fmaf(hr[k], s_cw[k * H1 + m], s);
            int node = g * NPG + nloc;
            float di = dinv[node];
            hws[node * H1 + m]  = s * di;        // pre-scaled by dinv[src]
            acc0[node * H1 + m] = s * (di * di); // self-loop term
        }
    }
}

// ======================= ELL gathers (int4 paired-entry reads) =======================
__device__ __forceinline__ void acc_msg(int r, float w, const float* __restrict__ hws,
                                        float4& mA, float4& mB) {
    const float4 ha = *reinterpret_cast<const float4*>(&hws[r * H1]);
    const float4 hb = *reinterpret_cast<const float4*>(&hws[r * H1 + 4]);
    mA.x = fmaf(ha.x, w, mA.x); mA.y = fmaf(ha.y, w, mA.y);
    mA.z = fmaf(ha.z, w, mA.z); mA.w = fmaf(ha.w, w, mA.w);
    mB.x = fmaf(hb.x, w, mB.x); mB.y = fmaf(hb.y, w, mB.y);
    mB.z = fmaf(hb.z, w, mB.z); mB.w = fmaf(hb.w, w, mB.w);
}

__global__ void k_gather0_ell(const int* __restrict__ cnt, const int2* __restrict__ ell,
                              const int* __restrict__ ovc, const int3* __restrict__ ovf,
                              const float* __restrict__ hws, const float* __restrict__ acc0,
                              const float* __restrict__ b0, const float* __restrict__ cw1,
                              const float* __restrict__ dinv, float* __restrict__ h1s) {
    int n = blockIdx.x * blockDim.x + threadIdx.x;
    if (n >= NNODES) return;
    int d = cnt[n];
    int m = d < MAXDEG ? d : MAXDEG;
    const int4* en4 = reinterpret_cast<const int4*>(&ell[(size_t)n * MAXDEG]);
    float4 mA = {0,0,0,0}, mB = {0,0,0,0};
    int h = m >> 1;
    for (int j = 0; j < h; ++j) {
        int4 pr = en4[j];
        acc_msg(pr.x, __int_as_float(pr.y), hws, mA, mB);
        acc_msg(pr.z, __int_as_float(pr.w), hws, mA, mB);
    }
    if (m & 1) {
        int2 ent = ell[(size_t)n * MAXDEG + m - 1];
        acc_msg(ent.x, __int_as_float(ent.y), hws, mA, mB);
    }
    if (d > MAXDEG) {
        int oc = *ovc; if (oc > OVCAP) oc = OVCAP;
        for (int j = 0; j < oc; ++j)
            if (ovf[j].x == n) acc_msg(ovf[j].y, __int_as_float(ovf[j].z), hws, mA, mB);
    }
    float dc = dinv[n];
    const float4 sA = *reinterpret_cast<const float4*>(&acc0[n * H1]);
    const float4 sB = *reinterpret_cast<const float4*>(&acc0[n * H1 + 4]);
    float s = 0.f;
    s = fmaf(elu(sA.x + dc * mA.x + b0[0]), cw1[0], s);
    s = fmaf(elu(sA.y + dc * mA.y + b0[1]), cw1[1], s);
    s = fmaf(elu(sA.z + dc * mA.z + b0[2]), cw1[2], s);
    s = fmaf(elu(sA.w + dc * mA.w + b0[3]), cw1[3], s);
    s = fmaf(elu(sB.x + dc * mB.x + b0[4]), cw1[4], s);
    s = fmaf(elu(sB.y + dc * mB.y + b0[5]), cw1[5], s);
    s = fmaf(elu(sB.z + dc * mB.z + b0[6]), cw1[6], s);
    s = fmaf(elu(sB.w + dc * mB.w + b0[7]), cw1[7], s);
    h1s[n] = s * dc;     // pre-scaled by dinv[src] for conv1
}

__global__ void k_gather1_ell(const int* __restrict__ cnt, const int2* __restrict__ ell,
                              const int* __restrict__ ovc, const int3* __restrict__ ovf,
                              const float* __restrict__ h1s, const float* __restrict__ dinv,
                              const float* __restrict__ cb1, float* __restrict__ out) {
    int n = blockIdx.x * blockDim.x + threadIdx.x;
    if (n >= NNODES) return;
    int d = cnt[n];
    int m = d < MAXDEG ? d : MAXDEG;
    const int4* en4 = reinterpret_cast<const int4*>(&ell[(size_t)n * MAXDEG]);
    float a = h1s[n];                    // self-loop term
    int h = m >> 1;
    for (int j = 0; j < h; ++j) {
        int4 pr = en4[j];
        a = fmaf(h1s[pr.x], __int_as_float(pr.y), a);
        a = fmaf(h1s[pr.z], __int_as_float(pr.w), a);
    }
    if (m & 1) {
        int2 ent = ell[(size_t)n * MAXDEG + m - 1];
        a = fmaf(h1s[ent.x], __int_as_float(ent.y), a);
    }
    if (d > MAXDEG) {
        int oc = *ovc; if (oc > OVCAP) oc = OVCAP;
        for (int j = 0; j < oc; ++j)
            if (ovf[j].x == n) a = fmaf(h1s[ovf[j].y], __int_as_float(ovf[j].z), a);
    }
    out[n] = cb1[0] + a * dinv[n];
}

// ======================= CSR fallback (round-4 pipeline, proven) =======================
__global__ void k_fc1(const float* __restrict__ x, const float* __restrict__ w,
                      const float* __restrict__ b, float* __restrict__ z1) {
    int t = threadIdx.x;
    int g = t >> 7, j = t & 127;
    float acc = b[j];
    #pragma unroll 8
    for (int i = 0; i < BNECK; ++i)
        acc = fmaf(x[g * BNECK + i], w[i * FFN + j], acc);
    z1[t] = elu(acc);
}

__global__ void k_zero(int* __restrict__ p, int n) {
    int i = blockIdx.x * blockDim.x + threadIdx.x;
    if (i < n) p[i] = 0;
}

__global__ void k_hist(const int* __restrict__ col, int* __restrict__ cnt) {
    int e = blockIdx.x * blockDim.x + threadIdx.x;
    if (e < NEDGE) atomicAdd(&cnt[col[e]], 1);
}

__global__ void k_bsum(const int* __restrict__ cnt, int* __restrict__ bsum) {
    __shared__ int s[SCAN_B];
    int t = threadIdx.x;
    int i = blockIdx.x * SCAN_B + t;
    s[t] = (i < NNODES) ? cnt[i] : 0;
    __syncthreads();
    for (int st = SCAN_B / 2; st > 0; st >>= 1) {
        if (t < st) s[t] += s[t + st];
        __syncthreads();
    }
    if (t == 0) bsum[blockIdx.x] = s[0];
}

__global__ void k_btop(const int* __restrict__ bsum, int* __restrict__ bstart) {
    __shared__ int s[SCAN_B];
    int t = threadIdx.x;
    int v = (t < NB) ? bsum[t] : 0;
    s[t] = v;
    __syncthreads();
    for (int st = 1; st < SCAN_B; st <<= 1) {
        int x = (t >= st) ? s[t - st] : 0;
        __syncthreads();
        s[t] += x;
        __syncthreads();
    }
    if (t < NB) bstart[t] = s[t] - v;
}

__global__ void k_bscan(int* __restrict__ cnt, const int* __restrict__ bstart) {
    __shared__ int s[SCAN_B];
    int t = threadIdx.x;
    int i = blockIdx.x * SCAN_B + t;
    int v = (i < NNODES) ? cnt[i] : 0;
    s[t] = v;
    __syncthreads();
    for (int st = 1; st < SCAN_B; st <<= 1) {
        int x = (t >= st) ? s[t - st] : 0;
        __syncthreads();
        s[t] += x;
        __syncthreads();
    }
    if (i < NNODES) cnt[i] = bstart[blockIdx.x] + s[t] - v;
}

__global__ void k_place(const int* __restrict__ row, const int* __restrict__ col,
                        const float* __restrict__ ew,
                        int* __restrict__ offs, int2* __restrict__ csr) {
    int e = blockIdx.x * blockDim.x + threadIdx.x;
    if (e >= NEDGE) return;
    int c = col[e];
    int pos = atomicAdd(&offs[c], 1);
    int2 ent;
    ent.x = row[e];
    ent.y = __float_as_int(ew[e]);
    csr[pos] = ent;
}

__global__ void k_deg(const int* __restrict__ offs, const int2* __restrict__ csr,
                      float* __restrict__ dinv) {
    int n = blockIdx.x * blockDim.x + threadIdx.x;
    if (n >= NNODES) return;
    int s0 = n ? offs[n - 1] : 0;
    int e0 = offs[n];
    float d = 1.0f;
    for (int j = s0; j < e0; ++j) d += __int_as_float(csr[j].y);
    dinv[n] = rsqrtf(d);
}

__global__ void k_gather0(const int* __restrict__ offs, const int2* __restrict__ csr,
                          const float* __restrict__ hws, const float* __restrict__ acc0,
                          const float* __restrict__ b0, const float* __restrict__ cw1,
                          const float* __restrict__ dinv, float* __restrict__ h1s) {
    int n = blockIdx.x * blockDim.x + threadIdx.x;
    if (n >= NNODES) return;
    int s0 = n ? offs[n - 1] : 0;
    int e0 = offs[n];
    float4 mA = {0,0,0,0}, mB = {0,0,0,0};
    for (int j = s0; j < e0; ++j) {
        int2 ent = csr[j];
        acc_msg(ent.x, __int_as_float(ent.y), hws, mA, mB);
    }
    float dc = dinv[n];
    const float4 sA = *reinterpret_cast<const float4*>(&acc0[n * H1]);
    const float4 sB = *reinterpret_cast<const float4*>(&acc0[n * H1 + 4]);
    float s = 0.f;
    s = fmaf(elu(sA.x + dc * mA.x + b0[0]), cw1[0], s);
    s = fmaf(elu(sA.y + dc * mA.y + b0[1]), cw1[1], s);
    s = fmaf(elu(sA.z + dc * mA.z + b0[2]), cw1[2], s);
    s = fmaf(elu(sA.w + dc * mA.w + b0[3]), cw1[3], s);
    s = fmaf(elu(sB.x + dc * mB.x + b0[4]), cw1[4], s);
    s = fmaf(elu(sB.y + dc * mB.y + b0[5]), cw1[5], s);
    s = fmaf(elu(sB.z + dc * mB.z + b0[6]), cw1[6], s);
    s = fmaf(elu(sB.w + dc * mB.w + b0[7]), cw1[7], s);
    h1s[n] = s * dc;
}

__global__ void k_gather1(const int* __restrict__ offs, const int2* __restrict__ csr,
                          const float* __restrict__ h1s, const float* __restrict__ dinv,
                          const float* __restrict__ cb1, float* __restrict__ out) {
    int n = blockIdx.x * blockDim.x + threadIdx.x;
    if (n >= NNODES) return;
    int s0 = n ? offs[n - 1] : 0;
    int e0 = offs[n];
    float a = h1s[n];
    for (int j = s0; j < e0; ++j) {
        int2 ent = csr[j];
        a = fmaf(h1s[ent.x], __int_as_float(ent.y), a);
    }
    out[n] = cb1[0] + a * dinv[n];
}

extern "C" void kernel_launch(void* const* d_in, const int* in_sizes, int n_in,
                              void* d_out, int out_size, void* d_ws, size_t ws_size,
                              hipStream_t stream) {
    const float* x    = (const float*)d_in[0];
    const int*   ei   = (const int*)d_in[1];
    const float* ew   = (const float*)d_in[2];
    const float* fc1w = (const float*)d_in[3];
    const float* fc1b = (const float*)d_in[4];
    const float* fc2w = (const float*)d_in[5];
    const float* fc2b = (const float*)d_in[6];
    const float* cw0  = (const float*)d_in[7];
    const float* cb0  = (const float*)d_in[8];
    const float* cw1  = (const float*)d_in[9];
    const float* cb1  = (const float*)d_in[10];
    float* out = (float*)d_out;

    const int* row = ei;
    const int* col = ei + NEDGE;

    // common workspace prefix (4B units)
    float* ws    = (float*)d_ws;
    float* z1    = ws;                          // 512
    float* dinv  = ws + 512;                    // 200000
    float* hws   = dinv + NNODES;               // 1.6M
    float* acc0  = hws + (size_t)NNODES * H1;   // 1.6M
    float* h1s   = acc0 + (size_t)NNODES * H1;  // 200000

    // ELL layout: prefix + cnt + ovc + ovf + ell
    size_t ell_units = 512 + NNODES + 2u * (size_t)NNODES * H1 + NNODES
                     + NNODES + 8 + (3u * OVCAP)
                     + 2u * (size_t)NNODES * MAXDEG;
    bool use_ell = ws_size >= ell_units * 4u + 256u;

    if (use_ell) {
        int*   cnt  = (int*)(h1s + NNODES);        // 200000
        int*   ovc  = (int*)(cnt + NNODES);        // 1 (+7 pad)
        int3*  ovf  = (int3*)(ovc + 8);            // 8192 x 12B
        int2*  ell  = (int2*)((int*)ovf + 3 * OVCAP); // 200000*32 x 8B

        k_init<<<1 + (NNODES + 511) / 512, 512, 0, stream>>>(x, fc1w, fc1b, z1, cnt, ovc);
        k_place_ell<<<2 * CH * 8, 256, 0, stream>>>(row, col, ew, cnt, ell, ovc, ovf);
        k_deg_ell<<<(NNODES + 255) / 256, 256, 0, stream>>>(cnt, ell, ovc, ovf, dinv);
        k_fc2<<<(COLS + 1023) / 1024, 256, 0, stream>>>(z1, fc2w, fc2b, cw0, dinv, hws, acc0);
        k_gather0_ell<<<(NNODES + 255) / 256, 256, 0, stream>>>(cnt, ell, ovc, ovf, hws, acc0,
                                                                cb0, cw1, dinv, h1s);
        k_gather1_ell<<<(NNODES + 255) / 256, 256, 0, stream>>>(cnt, ell, ovc, ovf, h1s, dinv,
                                                                cb1, out);
    } else {
        int*   offs  = (int*)(h1s + NNODES);        // 200000
        int*   bsum  = offs + NNODES;               // 512
        int*   bst   = bsum + SCAN_B;               // 512
        int2*  csr   = (int2*)(bst + SCAN_B);       // 3.2M x 8B

        k_fc1 <<<1, 512, 0, stream>>>(x, fc1w, fc1b, z1);
        k_zero<<<(NNODES + 255) / 256, 256, 0, stream>>>(offs, NNODES);
        k_hist<<<(NEDGE + 255) / 256, 256, 0, stream>>>(col, offs);
        k_bsum<<<NB, SCAN_B, 0, stream>>>(offs, bsum);
        k_btop<<<1, SCAN_B, 0, stream>>>(bsum, bst);
        k_bscan<<<NB, SCAN_B, 0, stream>>>(offs, bst);
        k_place<<<(NEDGE + 255) / 256, 256, 0, stream>>>(row, col, ew, offs, csr);
        k_deg<<<(NNODES + 255) / 256, 256, 0, stream>>>(offs, csr, dinv);
        k_fc2<<<(COLS + 1023) / 1024, 256, 0, stream>>>(z1, fc2w, fc2b, cw0, dinv, hws, acc0);
        k_gather0<<<(NNODES + 255) / 256, 256, 0, stream>>>(offs, csr, hws, acc0, cb0, cw1, dinv, h1s);
        k_gather1<<<(NNODES + 255) / 256, 256, 0, stream>>>(offs, csr, h1s, dinv, cb1, out);
    }
}